// Round 2
// baseline (605.576 us; speedup 1.0000x reference)
//
#include <hip/hip_runtime.h>
#include <hip/hip_bf16.h>

// Problem constants (AttentionalPlanarRemapping): N=32, C=64, H=W=128, E=512
#define NB   32
#define CC   64
#define HW   16384          // 128*128
#define EE   512
#define CC2  4096           // C*C

// ---------------------------------------------------------------------------
// Kernel 1: logits[n][j] = dot(atts[n,:], W[j,:]) + b[j]
// grid 512 blocks x 256 threads; thread handles one (n, j) pair.
// 4 independent accumulators break the 512-long dependent FMA chain.
// W (8 MiB) is read exactly once across the grid.
// ---------------------------------------------------------------------------
__global__ __launch_bounds__(256) void logits_kernel(
    const float* __restrict__ atts, const float* __restrict__ W,
    const float* __restrict__ b, float* __restrict__ logits) {
    const int t  = threadIdx.x;
    const int j  = blockIdx.x * 8 + (t & 7);
    const int n  = t >> 3;
    const float* __restrict__ wrow = W + (size_t)j * EE;
    const float* __restrict__ arow = atts + (size_t)n * EE;
    float acc0 = 0.f, acc1 = 0.f, acc2 = 0.f, acc3 = 0.f;
    #pragma unroll 4
    for (int k = 0; k < EE; k += 16) {
        float4 w0 = *reinterpret_cast<const float4*>(wrow + k);
        float4 a0 = *reinterpret_cast<const float4*>(arow + k);
        float4 w1 = *reinterpret_cast<const float4*>(wrow + k + 4);
        float4 a1 = *reinterpret_cast<const float4*>(arow + k + 4);
        float4 w2 = *reinterpret_cast<const float4*>(wrow + k + 8);
        float4 a2 = *reinterpret_cast<const float4*>(arow + k + 8);
        float4 w3 = *reinterpret_cast<const float4*>(wrow + k + 12);
        float4 a3 = *reinterpret_cast<const float4*>(arow + k + 12);
        acc0 = fmaf(w0.x, a0.x, acc0); acc0 = fmaf(w0.y, a0.y, acc0);
        acc0 = fmaf(w0.z, a0.z, acc0); acc0 = fmaf(w0.w, a0.w, acc0);
        acc1 = fmaf(w1.x, a1.x, acc1); acc1 = fmaf(w1.y, a1.y, acc1);
        acc1 = fmaf(w1.z, a1.z, acc1); acc1 = fmaf(w1.w, a1.w, acc1);
        acc2 = fmaf(w2.x, a2.x, acc2); acc2 = fmaf(w2.y, a2.y, acc2);
        acc2 = fmaf(w2.z, a2.z, acc2); acc2 = fmaf(w2.w, a2.w, acc2);
        acc3 = fmaf(w3.x, a3.x, acc3); acc3 = fmaf(w3.y, a3.y, acc3);
        acc3 = fmaf(w3.z, a3.z, acc3); acc3 = fmaf(w3.w, a3.w, acc3);
    }
    logits[(size_t)n * CC2 + j] = (acc0 + acc1) + (acc2 + acc3) + b[j];
}

// ---------------------------------------------------------------------------
// Kernel 2: first softmax over the flattened 4096, then per-row (64) softmax.
// One block per n. Second softmax uses all 256 threads: 4 threads per row,
// quad shuffle-reduce. Output stored TRANSPOSED: aT[n][d][c] = a[n][c][d].
// ---------------------------------------------------------------------------
__global__ __launch_bounds__(256) void softmax_kernel(
    const float* __restrict__ logits, float* __restrict__ aT) {
    const int n = blockIdx.x;
    const int t = threadIdx.x;
    __shared__ float s[CC2];
    __shared__ float wmax[4];
    __shared__ float wsum[4];

    const float* __restrict__ L = logits + (size_t)n * CC2;

    // load + thread-local max
    float lmax = -1e30f;
    for (int i = t; i < CC2; i += 256) {
        float v = L[i];
        s[i] = v;
        lmax = fmaxf(lmax, v);
    }
    #pragma unroll
    for (int off = 32; off > 0; off >>= 1) lmax = fmaxf(lmax, __shfl_xor(lmax, off));
    if ((t & 63) == 0) wmax[t >> 6] = lmax;
    __syncthreads();
    const float bmax = fmaxf(fmaxf(wmax[0], wmax[1]), fmaxf(wmax[2], wmax[3]));

    // exp + thread-local sum
    float lsum = 0.f;
    for (int i = t; i < CC2; i += 256) {
        float e = __expf(s[i] - bmax);
        s[i] = e;
        lsum += e;
    }
    #pragma unroll
    for (int off = 32; off > 0; off >>= 1) lsum += __shfl_xor(lsum, off);
    if ((t & 63) == 0) wsum[t >> 6] = lsum;
    __syncthreads();
    const float inv = 1.f / (wsum[0] + wsum[1] + wsum[2] + wsum[3]);

    for (int i = t; i < CC2; i += 256) s[i] *= inv;
    __syncthreads();

    // second softmax: 4 threads per row c, each covering 16 d's
    const int c = t >> 2;          // 0..63
    const int q = t & 3;           // 0..3
    const float* __restrict__ row = s + c * CC + q * 16;
    float mx = -1e30f;
    #pragma unroll
    for (int i = 0; i < 16; ++i) mx = fmaxf(mx, row[i]);
    mx = fmaxf(mx, __shfl_xor(mx, 1));
    mx = fmaxf(mx, __shfl_xor(mx, 2));
    float sum = 0.f;
    #pragma unroll
    for (int i = 0; i < 16; ++i) sum += __expf(row[i] - mx);
    sum += __shfl_xor(sum, 1);
    sum += __shfl_xor(sum, 2);
    const float isum = 1.f / sum;
    float* __restrict__ dst = aT + (size_t)n * CC2 + c;   // aT[n][d][c]
    #pragma unroll
    for (int i = 0; i < 16; ++i) dst[(q * 16 + i) * CC] = __expf(row[i] - mx) * isum;
}

// ---------------------------------------------------------------------------
// Kernel 3: out[n,c,px] = sum_d a[n,c,d] * img[n,d,px]
// grid (32 px-tiles, 32 n) x 256 threads. Each thread owns 2 pixels (float2),
// accumulates all 64 c in registers (128 VGPR acc — __launch_bounds__(256,3)
// grants ~170 VGPRs so no spill). aT[n] staged in LDS; per-d A-reads are 16
// wave-uniform ds_read_b128 broadcasts. Image read once, out written once.
// ---------------------------------------------------------------------------
__global__ __launch_bounds__(256, 3) void einsum_kernel(
    const float* __restrict__ img, const float* __restrict__ aT,
    float* __restrict__ out) {
    const int n  = blockIdx.y;
    const int t  = threadIdx.x;
    const int px0 = (blockIdx.x * 256 + t) * 2;

    __shared__ float4 sA[CC * CC / 4];   // sA[d*16+q] = a[n][4q..4q+3][d]
    {
        const float4* __restrict__ src = reinterpret_cast<const float4*>(aT + (size_t)n * CC2);
        #pragma unroll
        for (int i = 0; i < 4; ++i) sA[t + i * 256] = src[t + i * 256];
    }
    __syncthreads();

    float acc0[CC], acc1[CC];
    #pragma unroll
    for (int c = 0; c < CC; ++c) { acc0[c] = 0.f; acc1[c] = 0.f; }

    const float* __restrict__ ip = img + (size_t)n * CC * HW + px0;
    #pragma unroll 2
    for (int d = 0; d < CC; ++d) {
        const float2 v = *reinterpret_cast<const float2*>(ip + (size_t)d * HW);
        #pragma unroll
        for (int q = 0; q < 16; ++q) {
            const float4 a4 = sA[d * 16 + q];
            acc0[4 * q + 0] = fmaf(a4.x, v.x, acc0[4 * q + 0]);
            acc1[4 * q + 0] = fmaf(a4.x, v.y, acc1[4 * q + 0]);
            acc0[4 * q + 1] = fmaf(a4.y, v.x, acc0[4 * q + 1]);
            acc1[4 * q + 1] = fmaf(a4.y, v.y, acc1[4 * q + 1]);
            acc0[4 * q + 2] = fmaf(a4.z, v.x, acc0[4 * q + 2]);
            acc1[4 * q + 2] = fmaf(a4.z, v.y, acc1[4 * q + 2]);
            acc0[4 * q + 3] = fmaf(a4.w, v.x, acc0[4 * q + 3]);
            acc1[4 * q + 3] = fmaf(a4.w, v.y, acc1[4 * q + 3]);
        }
    }

    float* __restrict__ op = out + (size_t)n * CC * HW + px0;
    #pragma unroll
    for (int c = 0; c < CC; ++c) {
        float2 r;
        r.x = acc0[c];
        r.y = acc1[c];
        *reinterpret_cast<float2*>(op + (size_t)c * HW) = r;
    }
}

// ---------------------------------------------------------------------------
extern "C" void kernel_launch(void* const* d_in, const int* in_sizes, int n_in,
                              void* d_out, int out_size, void* d_ws, size_t ws_size,
                              hipStream_t stream) {
    const float* images = (const float*)d_in[0];   // [32,64,128,128]
    const float* atts   = (const float*)d_in[1];   // [32,512]
    const float* W      = (const float*)d_in[2];   // [4096,512]
    const float* b      = (const float*)d_in[3];   // [4096]
    float* out = (float*)d_out;                    // [32,64,128,128]

    // workspace: logits [32*4096] + aT [32*4096]  (1 MiB total)
    float* logits = (float*)d_ws;
    float* aT     = logits + NB * CC2;

    logits_kernel<<<CC2 / 8, 256, 0, stream>>>(atts, W, b, logits);
    softmax_kernel<<<NB, 256, 0, stream>>>(logits, aT);
    einsum_kernel<<<dim3(HW / 512, NB), 256, 0, stream>>>(images, aT, out);
}

// Round 3
// 127.287 us; speedup vs baseline: 4.7576x; 4.7576x over previous
//
#include <hip/hip_runtime.h>
#include <hip/hip_bf16.h>

// Problem constants (AttentionalPlanarRemapping): N=32, C=64, H=W=128, E=512
#define NB   32
#define CC   64
#define HW   16384          // 128*128
#define EE   512
#define CC2  4096           // C*C

// ---------------------------------------------------------------------------
// Kernel 1: logits[n][j] = dot(atts[n,:], W[j,:]) + b[j]
// 1024 blocks x 256 threads. Block covers 4 j's x 32 n x 2 k-halves.
// Each thread does a 256-long half-dot; halves combined via LDS.
// W (8 MiB) is read exactly once across the grid.
// ---------------------------------------------------------------------------
__global__ __launch_bounds__(256) void logits_kernel(
    const float* __restrict__ atts, const float* __restrict__ W,
    const float* __restrict__ b, float* __restrict__ logits) {
    const int t  = threadIdx.x;
    const int j  = blockIdx.x * 4 + (t & 3);
    const int n  = (t >> 2) & 31;
    const int kh = t >> 7;                 // 0 or 1
    const float* __restrict__ wrow = W + (size_t)j * EE + kh * 256;
    const float* __restrict__ arow = atts + (size_t)n * EE + kh * 256;
    float acc0 = 0.f, acc1 = 0.f;
    #pragma unroll 4
    for (int k = 0; k < 256; k += 8) {
        float4 w0 = *reinterpret_cast<const float4*>(wrow + k);
        float4 a0 = *reinterpret_cast<const float4*>(arow + k);
        float4 w1 = *reinterpret_cast<const float4*>(wrow + k + 4);
        float4 a1 = *reinterpret_cast<const float4*>(arow + k + 4);
        acc0 = fmaf(w0.x, a0.x, acc0); acc0 = fmaf(w0.y, a0.y, acc0);
        acc0 = fmaf(w0.z, a0.z, acc0); acc0 = fmaf(w0.w, a0.w, acc0);
        acc1 = fmaf(w1.x, a1.x, acc1); acc1 = fmaf(w1.y, a1.y, acc1);
        acc1 = fmaf(w1.z, a1.z, acc1); acc1 = fmaf(w1.w, a1.w, acc1);
    }
    __shared__ float part[256];
    part[t] = acc0 + acc1;
    __syncthreads();
    if (t < 128) {
        logits[(size_t)n * CC2 + j] = part[t] + part[t + 128] + b[j];
    }
}

// ---------------------------------------------------------------------------
// Kernel 2: first softmax over the flattened 4096, then per-row (64) softmax.
// One block per n. Second softmax uses all 256 threads: 4 threads per row,
// quad shuffle-reduce. Output stored TRANSPOSED: aT[n][d][c] = a[n][c][d].
// ---------------------------------------------------------------------------
__global__ __launch_bounds__(256) void softmax_kernel(
    const float* __restrict__ logits, float* __restrict__ aT) {
    const int n = blockIdx.x;
    const int t = threadIdx.x;
    __shared__ float s[CC2];
    __shared__ float wmax[4];
    __shared__ float wsum[4];

    const float* __restrict__ L = logits + (size_t)n * CC2;

    // load + thread-local max
    float lmax = -1e30f;
    for (int i = t; i < CC2; i += 256) {
        float v = L[i];
        s[i] = v;
        lmax = fmaxf(lmax, v);
    }
    #pragma unroll
    for (int off = 32; off > 0; off >>= 1) lmax = fmaxf(lmax, __shfl_xor(lmax, off));
    if ((t & 63) == 0) wmax[t >> 6] = lmax;
    __syncthreads();
    const float bmax = fmaxf(fmaxf(wmax[0], wmax[1]), fmaxf(wmax[2], wmax[3]));

    // exp + thread-local sum
    float lsum = 0.f;
    for (int i = t; i < CC2; i += 256) {
        float e = __expf(s[i] - bmax);
        s[i] = e;
        lsum += e;
    }
    #pragma unroll
    for (int off = 32; off > 0; off >>= 1) lsum += __shfl_xor(lsum, off);
    if ((t & 63) == 0) wsum[t >> 6] = lsum;
    __syncthreads();
    const float inv = 1.f / (wsum[0] + wsum[1] + wsum[2] + wsum[3]);

    for (int i = t; i < CC2; i += 256) s[i] *= inv;
    __syncthreads();

    // second softmax: 4 threads per row c, each covering 16 d's
    const int c = t >> 2;          // 0..63
    const int q = t & 3;           // 0..3
    const float* __restrict__ row = s + c * CC + q * 16;
    float mx = -1e30f;
    #pragma unroll
    for (int i = 0; i < 16; ++i) mx = fmaxf(mx, row[i]);
    mx = fmaxf(mx, __shfl_xor(mx, 1));
    mx = fmaxf(mx, __shfl_xor(mx, 2));
    float sum = 0.f;
    #pragma unroll
    for (int i = 0; i < 16; ++i) sum += __expf(row[i] - mx);
    sum += __shfl_xor(sum, 1);
    sum += __shfl_xor(sum, 2);
    const float isum = 1.f / sum;
    float* __restrict__ dst = aT + (size_t)n * CC2 + c;   // aT[n][d][c]
    #pragma unroll
    for (int i = 0; i < 16; ++i) dst[(q * 16 + i) * CC] = __expf(row[i] - mx) * isum;
}

// ---------------------------------------------------------------------------
// Kernel 3: out[n,c,px] = sum_d a[n,c,d] * img[n,d,px]
// grid (128 px-tiles, 32 n) x 256 threads. Threads = 8 c-groups x 32 px.
// Each thread: 8 c x 4 px = 32 register accumulators (fits ~70 VGPR, high
// occupancy, no spill). Per d-step: 1 coalesced float4 image load + 2
// wave-uniform ds_read_b128 of a-values + 32 FMAs. Image read once from HBM
// (c-group re-reads are L1 hits); output written once, coalesced float4.
// ---------------------------------------------------------------------------
__global__ __launch_bounds__(256) void einsum_kernel(
    const float* __restrict__ img, const float* __restrict__ aT,
    float* __restrict__ out) {
    const int n  = blockIdx.y;
    const int t  = threadIdx.x;
    const int cg = t >> 5;                       // 0..7 c-group
    const int pt = t & 31;                       // 0..31 px-thread
    const int px0 = blockIdx.x * 128 + pt * 4;
    const int c0 = cg * 8;

    __shared__ float4 sA[CC * CC / 4];           // sA[d*16 + c/4] = aT[n][d][c..c+3]
    {
        const float4* __restrict__ src = reinterpret_cast<const float4*>(aT + (size_t)n * CC2);
        #pragma unroll
        for (int i = 0; i < 4; ++i) sA[t + i * 256] = src[t + i * 256];
    }
    __syncthreads();

    float acc[8][4];
    #pragma unroll
    for (int c = 0; c < 8; ++c) {
        #pragma unroll
        for (int p = 0; p < 4; ++p) acc[c][p] = 0.f;
    }

    const float* __restrict__ ip = img + (size_t)n * CC * HW + px0;
    const float4* __restrict__ sAr = sA + cg * 2;    // + d*16 per step

    #pragma unroll 2
    for (int d = 0; d < CC; ++d) {
        const float4 v  = *reinterpret_cast<const float4*>(ip + (size_t)d * HW);
        const float4 a0 = sAr[d * 16];
        const float4 a1 = sAr[d * 16 + 1];
        const float av[8] = {a0.x, a0.y, a0.z, a0.w, a1.x, a1.y, a1.z, a1.w};
        #pragma unroll
        for (int c = 0; c < 8; ++c) {
            acc[c][0] = fmaf(av[c], v.x, acc[c][0]);
            acc[c][1] = fmaf(av[c], v.y, acc[c][1]);
            acc[c][2] = fmaf(av[c], v.z, acc[c][2]);
            acc[c][3] = fmaf(av[c], v.w, acc[c][3]);
        }
    }

    float* __restrict__ op = out + (size_t)n * CC * HW + (size_t)c0 * HW + px0;
    #pragma unroll
    for (int c = 0; c < 8; ++c) {
        float4 r;
        r.x = acc[c][0]; r.y = acc[c][1]; r.z = acc[c][2]; r.w = acc[c][3];
        *reinterpret_cast<float4*>(op + (size_t)c * HW) = r;
    }
}

// ---------------------------------------------------------------------------
extern "C" void kernel_launch(void* const* d_in, const int* in_sizes, int n_in,
                              void* d_out, int out_size, void* d_ws, size_t ws_size,
                              hipStream_t stream) {
    const float* images = (const float*)d_in[0];   // [32,64,128,128]
    const float* atts   = (const float*)d_in[1];   // [32,512]
    const float* W      = (const float*)d_in[2];   // [4096,512]
    const float* b      = (const float*)d_in[3];   // [4096]
    float* out = (float*)d_out;                    // [32,64,128,128]

    // workspace: logits [32*4096] + aT [32*4096]  (1 MiB total)
    float* logits = (float*)d_ws;
    float* aT     = logits + NB * CC2;

    logits_kernel<<<CC2 / 4, 256, 0, stream>>>(atts, W, b, logits);
    softmax_kernel<<<NB, 256, 0, stream>>>(logits, aT);
    einsum_kernel<<<dim3(HW / 128, NB), 256, 0, stream>>>(images, aT, out);
}